// Round 1
// baseline (137.091 us; speedup 1.0000x reference)
//
#include <hip/hip_runtime.h>
#include <math.h>

#define KS    5
#define K2    25
#define BB    4
#define HH    256
#define WW    256
#define PLANE (HH * WW)
#define LROWD 264     // dwords per tile row: [2 halo][256 px][2 halo][4 pad]
#define PTILE 1864    // 7 rows * 264 + 16 pad; %32==8 -> cg stride (2*PTILE) == 16 banks
#define NTHR  512

typedef __attribute__((ext_vector_type(2))) _Float16 half2_t;

static __device__ __forceinline__ half2_t u2h(unsigned u) { return __builtin_bit_cast(half2_t, u); }

static __device__ __forceinline__ unsigned pkrtz(float a, float b) {
    auto h = __builtin_amdgcn_cvt_pkrtz(a, b);   // __fp16 ext_vector(2), 4 bytes
    return __builtin_bit_cast(unsigned, h);
}

static __device__ __forceinline__ float dot2(half2_t a, half2_t b, float c) {
#if __has_builtin(__builtin_amdgcn_fdot2)
    return __builtin_amdgcn_fdot2(a, b, c, false);
#else
    return (float)a.x * (float)b.x + ((float)a.y * (float)b.y + c);
#endif
}

// Block = 2 output rows x 256 cols, 8 waves, 2 px/thread, channel-pair f16 tile.
// vs previous version (4 px/thread, 4 waves): halving px/thread halves the
// score accumulator (s[2][25]=50 VGPR vs 100) and prefetch regs (24 vs 48),
// fitting 4 waves/SIMD (<=128 VGPR) -> 16 resident waves/CU instead of 8.
// Grid stays 512 blocks = exactly 2 blocks/CU, no occupancy tail.
// 8 stages x 8 channels (score: 32..63, output: 0..31), double-buffered LDS.
// Tile dword = half2(ch c, ch c+1) per pixel -> 3 ds_read_b64 per window row
// (64 lanes x 2 dwords, half-wave PTILE offset %32==16 banks -> conflict-free),
// v_dot2 = 2 MACs/instr for scores. Zeroed halo/OOB rows => implicit padding.
__global__ __launch_bounds__(NTHR, 4)
void local_attn_kernel(const float* __restrict__ x,
                       const float* __restrict__ kern,
                       float* __restrict__ out)
{
    __shared__ unsigned ldsu[2 * 4 * PTILE];
    __shared__ float kw[K2];

    const int tid = threadIdx.x;
    for (int i = tid; i < 2 * 4 * PTILE; i += NTHR) ldsu[i] = 0u;
    if (tid < K2) kw[tid] = kern[tid] * (1.0f / KS);

    const int lane = tid & 63;
    const int wv   = tid >> 6;                      // 0..7
    const int ty   = wv >> 2;                       // output row in block (0..1)
    const int cg   = lane >> 5;                     // pair-half (0/1)
    const int tx   = ((wv & 3) << 5) | (lane & 31); // pixel-group 0..127
    const int w0   = tx << 1;                       // px base (== tile dword base)

    // XCD swizzle: each XCD owns a contiguous 32-row band (halo L2-shared)
    const int bx     = blockIdx.x;
    const int hgroup = ((bx & 7) << 4) | (bx >> 3);
    const int h0     = hgroup * 2;
    const int h      = h0 + ty;
    const int b      = blockIdx.y;

    const float* xb = x + (size_t)b * 64 * PLANE;

    // 3 staging tasks/thread: task i -> (pair, tile row, 4-px segment)
    int gofs[3], lofs[3], pofs[3];
#pragma unroll
    for (int i = 0; i < 3; ++i) {
        const int rp   = (tid >> 6) + 8 * i;        // 0..23 (wave-uniform)
        const int row  = rp % 6;
        const int pair = rp / 6;
        const int r    = h0 - 2 + row;
        const bool v   = (unsigned)r < (unsigned)HH;
        gofs[i] = min(max(r, 0), HH - 1) * WW + (tid & 63) * 4;
        pofs[i] = pair * 2 * PLANE;
        lofs[i] = pair * PTILE + (v ? row : 6) * LROWD + 2 + (tid & 63) * 4;
    }

    float4 pa[3], pb[3];
    auto prefetch = [&](int st) {
        const float* xc = xb + (size_t)((st < 4) ? 32 + st * 8 : (st - 4) * 8) * PLANE;
#pragma unroll
        for (int i = 0; i < 3; ++i) {
            pa[i] = *(const float4*)(xc + pofs[i] + gofs[i]);
            pb[i] = *(const float4*)(xc + pofs[i] + PLANE + gofs[i]);
        }
    };
    auto cvtwrite = [&](int bufi) {
        unsigned* lb = ldsu + bufi * 4 * PTILE;
#pragma unroll
        for (int i = 0; i < 3; ++i) {
            const unsigned d0 = pkrtz(pa[i].x, pb[i].x);
            const unsigned d1 = pkrtz(pa[i].y, pb[i].y);
            const unsigned d2 = pkrtz(pa[i].z, pb[i].z);
            const unsigned d3 = pkrtz(pa[i].w, pb[i].w);
            *(uint2*)(lb + lofs[i])     = make_uint2(d0, d1);
            *(uint2*)(lb + lofs[i] + 2) = make_uint2(d2, d3);
        }
    };

    float s[2][K2];
#pragma unroll
    for (int p = 0; p < 2; ++p)
#pragma unroll
        for (int k = 0; k < K2; ++k) s[p][k] = 0.0f;

    __syncthreads();          // zero-init + kw visible
    prefetch(0);
    cvtwrite(0);
    __syncthreads();

#pragma unroll 1
    for (int t = 0; t < 8; ++t) {
        if (t + 1 < 8) prefetch(t + 1);
        const unsigned* buf = ldsu + (t & 1) * 4 * PTILE;

        if (t < 4) {
            // ---- score: 2 channel-pairs per lane-half, dot2 accumulate ----
#pragma unroll
            for (int dp = 0; dp < 2; ++dp) {
                const unsigned* tb = buf + (cg * 2 + dp) * PTILE;
                half2_t ctr[2];
                {   // center row (i=2) first: f[q] = pair at px w0-2+q
                    const unsigned* rp = tb + (ty + 2) * LROWD + w0;
                    const uint2 r0 = *(const uint2*)(rp);
                    const uint2 r1 = *(const uint2*)(rp + 2);
                    const uint2 r2 = *(const uint2*)(rp + 4);
                    half2_t f[6] = {u2h(r0.x), u2h(r0.y), u2h(r1.x),
                                    u2h(r1.y), u2h(r2.x), u2h(r2.y)};
                    ctr[0] = f[2];
                    ctr[1] = f[3];
#pragma unroll
                    for (int j = 0; j < KS; ++j)
#pragma unroll
                        for (int p = 0; p < 2; ++p)
                            s[p][2 * KS + j] = dot2(f[p + j], ctr[p], s[p][2 * KS + j]);
                }
#pragma unroll
                for (int i = 0; i < KS; ++i) {
                    if (i == 2) continue;
                    const unsigned* rp = tb + (ty + i) * LROWD + w0;
                    const uint2 r0 = *(const uint2*)(rp);
                    const uint2 r1 = *(const uint2*)(rp + 2);
                    const uint2 r2 = *(const uint2*)(rp + 4);
                    half2_t f[6] = {u2h(r0.x), u2h(r0.y), u2h(r1.x),
                                    u2h(r1.y), u2h(r2.x), u2h(r2.y)};
#pragma unroll
                    for (int j = 0; j < KS; ++j)
#pragma unroll
                        for (int p = 0; p < 2; ++p)
                            s[p][i * KS + j] = dot2(f[p + j], ctr[p], s[p][i * KS + j]);
                }
            }
            if (t == 3) {
                // combine pair-halves, then softmax over 25 taps.
                // zero-padded taps score exactly 0 and keep their denominator
                // share (matches reference).
#pragma unroll
                for (int p = 0; p < 2; ++p)
#pragma unroll
                    for (int k = 0; k < K2; ++k)
                        s[p][k] += __shfl_xor(s[p][k], 32, 64);
#pragma unroll
                for (int p = 0; p < 2; ++p) {
                    float mx = -INFINITY;
#pragma unroll
                    for (int k = 0; k < K2; ++k) {
                        float v = s[p][k] * kw[k];
                        s[p][k] = v;
                        mx = fmaxf(mx, v);
                    }
                    float sum = 0.0f;
#pragma unroll
                    for (int k = 0; k < K2; ++k) {
                        float e = __expf(s[p][k] - mx);
                        s[p][k] = e;
                        sum += e;
                    }
                    const float inv = 1.0f / sum;
#pragma unroll
                    for (int k = 0; k < K2; ++k) s[p][k] *= inv;
                }
            }
        } else {
            // ---- output: weighted sum; fp32 accumulate via mixed FMA ----
            const int chb = (t - 4) * 8;
#pragma unroll
            for (int dp = 0; dp < 2; ++dp) {
                const unsigned* tb = buf + (cg * 2 + dp) * PTILE;
                float alo[2] = {0.f, 0.f};
                float ahi[2] = {0.f, 0.f};
#pragma unroll
                for (int i = 0; i < KS; ++i) {
                    const unsigned* rp = tb + (ty + i) * LROWD + w0;
                    const uint2 r0 = *(const uint2*)(rp);
                    const uint2 r1 = *(const uint2*)(rp + 2);
                    const uint2 r2 = *(const uint2*)(rp + 4);
                    half2_t f[6] = {u2h(r0.x), u2h(r0.y), u2h(r1.x),
                                    u2h(r1.y), u2h(r2.x), u2h(r2.y)};
#pragma unroll
                    for (int j = 0; j < KS; ++j)
#pragma unroll
                        for (int p = 0; p < 2; ++p) {
                            const half2_t v = f[p + j];
                            const float  wgt = s[p][i * KS + j];
                            alo[p] = fmaf((float)v.x, wgt, alo[p]);
                            ahi[p] = fmaf((float)v.y, wgt, ahi[p]);
                        }
                }
                const int c0 = chb + (cg * 2 + dp) * 2;
                float* op = out + ((size_t)b * 32 + c0) * PLANE + h * WW + w0;
                *(float2*)op           = make_float2(alo[0], alo[1]);
                *(float2*)(op + PLANE) = make_float2(ahi[0], ahi[1]);
            }
        }

        if (t + 1 < 8) {
            cvtwrite((t + 1) & 1);
            __syncthreads();
        }
    }
}

extern "C" void kernel_launch(void* const* d_in, const int* in_sizes, int n_in,
                              void* d_out, int out_size, void* d_ws, size_t ws_size,
                              hipStream_t stream) {
    const float* x    = (const float*)d_in[0];
    const float* kern = (const float*)d_in[1];
    float*       out  = (float*)d_out;

    dim3 grid(HH / 2, BB, 1);
    dim3 block(NTHR, 1, 1);
    hipLaunchKernelGGL(local_attn_kernel, grid, block, 0, stream, x, kern, out);
}

// Round 2
// 116.380 us; speedup vs baseline: 1.1780x; 1.1780x over previous
//
#include <hip/hip_runtime.h>
#include <math.h>

#define KS    5
#define K2    25
#define BB    4
#define HH    256
#define WW    256
#define PLANE (HH * WW)
#define LROWD 264     // dwords per tile row: [2 halo][256 px][2 halo][4 pad]
#define PTILE 1864    // 7 rows * 264 + 16 pad; %32==8 -> cg stride (2*PTILE) == 16 banks
#define NTHR  512

typedef __attribute__((ext_vector_type(2))) _Float16 half2_t;

static __device__ __forceinline__ half2_t u2h(unsigned u) { return __builtin_bit_cast(half2_t, u); }

static __device__ __forceinline__ unsigned pkrtz(float a, float b) {
    auto h = __builtin_amdgcn_cvt_pkrtz(a, b);   // __fp16 ext_vector(2), 4 bytes
    return __builtin_bit_cast(unsigned, h);
}

static __device__ __forceinline__ float dot2(half2_t a, half2_t b, float c) {
#if __has_builtin(__builtin_amdgcn_fdot2)
    return __builtin_amdgcn_fdot2(a, b, c, false);
#else
    return (float)a.x * (float)b.x + ((float)a.y * (float)b.y + c);
#endif
}

// Block = 2 output rows x 256 cols, 8 waves, 2 px/thread, channel-pair f16 tile.
// LAUNCH BOUNDS NOTE: hipcc treats the 2nd arg as min BLOCKS/CU (CUDA
// convention): (512,4) -> 32 waves/CU -> 64-VGPR budget -> catastrophic
// scratch spill (+50MB WRITE_SIZE, VALUBusy 24%). (512,2) -> 16 waves/CU
// -> 128-VGPR budget, which fits the ~110-reg live set. Occupancy is then
// LDS-limited at 2 blocks/CU = 4 waves/SIMD (2x the 4-wave baseline).
// 8 stages x 8 channels (score: 32..63, output: 0..31), double-buffered LDS.
// Tile dword = half2(ch c, ch c+1) per pixel -> 3 ds_read_b64 per window row
// (64 lanes x 2 dwords, half-wave PTILE offset %32==16 banks -> conflict-free),
// v_dot2 = 2 MACs/instr for scores. Zeroed halo/OOB rows => implicit padding.
__global__ __launch_bounds__(NTHR, 2)
void local_attn_kernel(const float* __restrict__ x,
                       const float* __restrict__ kern,
                       float* __restrict__ out)
{
    __shared__ unsigned ldsu[2 * 4 * PTILE];
    __shared__ float kw[K2];

    const int tid = threadIdx.x;
    for (int i = tid; i < 2 * 4 * PTILE; i += NTHR) ldsu[i] = 0u;
    if (tid < K2) kw[tid] = kern[tid] * (1.0f / KS);

    const int lane = tid & 63;
    const int wv   = tid >> 6;                      // 0..7
    const int ty   = wv >> 2;                       // output row in block (0..1)
    const int cg   = lane >> 5;                     // pair-half (0/1)
    const int tx   = ((wv & 3) << 5) | (lane & 31); // pixel-group 0..127
    const int w0   = tx << 1;                       // px base (== tile dword base)

    // XCD swizzle: each XCD owns a contiguous 32-row band (halo L2-shared)
    const int bx     = blockIdx.x;
    const int hgroup = ((bx & 7) << 4) | (bx >> 3);
    const int h0     = hgroup * 2;
    const int h      = h0 + ty;
    const int b      = blockIdx.y;

    const float* xb = x + (size_t)b * 64 * PLANE;

    // 3 staging tasks/thread: task i -> (pair, tile row, 4-px segment)
    int gofs[3], lofs[3], pofs[3];
#pragma unroll
    for (int i = 0; i < 3; ++i) {
        const int rp   = (tid >> 6) + 8 * i;        // 0..23 (wave-uniform)
        const int row  = rp % 6;
        const int pair = rp / 6;
        const int r    = h0 - 2 + row;
        const bool v   = (unsigned)r < (unsigned)HH;
        gofs[i] = min(max(r, 0), HH - 1) * WW + (tid & 63) * 4;
        pofs[i] = pair * 2 * PLANE;
        lofs[i] = pair * PTILE + (v ? row : 6) * LROWD + 2 + (tid & 63) * 4;
    }

    float4 pa[3], pb[3];
    auto prefetch = [&](int st) {
        const float* xc = xb + (size_t)((st < 4) ? 32 + st * 8 : (st - 4) * 8) * PLANE;
#pragma unroll
        for (int i = 0; i < 3; ++i) {
            pa[i] = *(const float4*)(xc + pofs[i] + gofs[i]);
            pb[i] = *(const float4*)(xc + pofs[i] + PLANE + gofs[i]);
        }
    };
    auto cvtwrite = [&](int bufi) {
        unsigned* lb = ldsu + bufi * 4 * PTILE;
#pragma unroll
        for (int i = 0; i < 3; ++i) {
            const unsigned d0 = pkrtz(pa[i].x, pb[i].x);
            const unsigned d1 = pkrtz(pa[i].y, pb[i].y);
            const unsigned d2 = pkrtz(pa[i].z, pb[i].z);
            const unsigned d3 = pkrtz(pa[i].w, pb[i].w);
            *(uint2*)(lb + lofs[i])     = make_uint2(d0, d1);
            *(uint2*)(lb + lofs[i] + 2) = make_uint2(d2, d3);
        }
    };

    float s[2][K2];
#pragma unroll
    for (int p = 0; p < 2; ++p)
#pragma unroll
        for (int k = 0; k < K2; ++k) s[p][k] = 0.0f;

    __syncthreads();          // zero-init + kw visible
    prefetch(0);
    cvtwrite(0);
    __syncthreads();

#pragma unroll 1
    for (int t = 0; t < 8; ++t) {
        if (t + 1 < 8) prefetch(t + 1);
        const unsigned* buf = ldsu + (t & 1) * 4 * PTILE;

        if (t < 4) {
            // ---- score: 2 channel-pairs per lane-half, dot2 accumulate ----
#pragma unroll
            for (int dp = 0; dp < 2; ++dp) {
                const unsigned* tb = buf + (cg * 2 + dp) * PTILE;
                half2_t ctr[2];
                {   // center row (i=2) first: f[q] = pair at px w0-2+q
                    const unsigned* rp = tb + (ty + 2) * LROWD + w0;
                    const uint2 r0 = *(const uint2*)(rp);
                    const uint2 r1 = *(const uint2*)(rp + 2);
                    const uint2 r2 = *(const uint2*)(rp + 4);
                    half2_t f[6] = {u2h(r0.x), u2h(r0.y), u2h(r1.x),
                                    u2h(r1.y), u2h(r2.x), u2h(r2.y)};
                    ctr[0] = f[2];
                    ctr[1] = f[3];
#pragma unroll
                    for (int j = 0; j < KS; ++j)
#pragma unroll
                        for (int p = 0; p < 2; ++p)
                            s[p][2 * KS + j] = dot2(f[p + j], ctr[p], s[p][2 * KS + j]);
                }
#pragma unroll
                for (int i = 0; i < KS; ++i) {
                    if (i == 2) continue;
                    const unsigned* rp = tb + (ty + i) * LROWD + w0;
                    const uint2 r0 = *(const uint2*)(rp);
                    const uint2 r1 = *(const uint2*)(rp + 2);
                    const uint2 r2 = *(const uint2*)(rp + 4);
                    half2_t f[6] = {u2h(r0.x), u2h(r0.y), u2h(r1.x),
                                    u2h(r1.y), u2h(r2.x), u2h(r2.y)};
#pragma unroll
                    for (int j = 0; j < KS; ++j)
#pragma unroll
                        for (int p = 0; p < 2; ++p)
                            s[p][i * KS + j] = dot2(f[p + j], ctr[p], s[p][i * KS + j]);
                }
            }
            if (t == 3) {
                // combine pair-halves, then softmax over 25 taps.
                // zero-padded taps score exactly 0 and keep their denominator
                // share (matches reference).
#pragma unroll
                for (int p = 0; p < 2; ++p)
#pragma unroll
                    for (int k = 0; k < K2; ++k)
                        s[p][k] += __shfl_xor(s[p][k], 32, 64);
#pragma unroll
                for (int p = 0; p < 2; ++p) {
                    float mx = -INFINITY;
#pragma unroll
                    for (int k = 0; k < K2; ++k) {
                        float v = s[p][k] * kw[k];
                        s[p][k] = v;
                        mx = fmaxf(mx, v);
                    }
                    float sum = 0.0f;
#pragma unroll
                    for (int k = 0; k < K2; ++k) {
                        float e = __expf(s[p][k] - mx);
                        s[p][k] = e;
                        sum += e;
                    }
                    const float inv = 1.0f / sum;
#pragma unroll
                    for (int k = 0; k < K2; ++k) s[p][k] *= inv;
                }
            }
        } else {
            // ---- output: weighted sum; fp32 accumulate via mixed FMA ----
            const int chb = (t - 4) * 8;
#pragma unroll
            for (int dp = 0; dp < 2; ++dp) {
                const unsigned* tb = buf + (cg * 2 + dp) * PTILE;
                float alo[2] = {0.f, 0.f};
                float ahi[2] = {0.f, 0.f};
#pragma unroll
                for (int i = 0; i < KS; ++i) {
                    const unsigned* rp = tb + (ty + i) * LROWD + w0;
                    const uint2 r0 = *(const uint2*)(rp);
                    const uint2 r1 = *(const uint2*)(rp + 2);
                    const uint2 r2 = *(const uint2*)(rp + 4);
                    half2_t f[6] = {u2h(r0.x), u2h(r0.y), u2h(r1.x),
                                    u2h(r1.y), u2h(r2.x), u2h(r2.y)};
#pragma unroll
                    for (int j = 0; j < KS; ++j)
#pragma unroll
                        for (int p = 0; p < 2; ++p) {
                            const half2_t v = f[p + j];
                            const float  wgt = s[p][i * KS + j];
                            alo[p] = fmaf((float)v.x, wgt, alo[p]);
                            ahi[p] = fmaf((float)v.y, wgt, ahi[p]);
                        }
                }
                const int c0 = chb + (cg * 2 + dp) * 2;
                float* op = out + ((size_t)b * 32 + c0) * PLANE + h * WW + w0;
                *(float2*)op           = make_float2(alo[0], alo[1]);
                *(float2*)(op + PLANE) = make_float2(ahi[0], ahi[1]);
            }
        }

        if (t + 1 < 8) {
            cvtwrite((t + 1) & 1);
            __syncthreads();
        }
    }
}

extern "C" void kernel_launch(void* const* d_in, const int* in_sizes, int n_in,
                              void* d_out, int out_size, void* d_ws, size_t ws_size,
                              hipStream_t stream) {
    const float* x    = (const float*)d_in[0];
    const float* kern = (const float*)d_in[1];
    float*       out  = (float*)d_out;

    dim3 grid(HH / 2, BB, 1);
    dim3 block(NTHR, 1, 1);
    hipLaunchKernelGGL(local_attn_kernel, grid, block, 0, stream, x, kern, out);
}

// Round 3
// 114.915 us; speedup vs baseline: 1.1930x; 1.0128x over previous
//
#include <hip/hip_runtime.h>
#include <math.h>

#define KS    5
#define K2    25
#define BB    4
#define HH    256
#define WW    256
#define PLANE (HH * WW)
#define LROWD 264     // dwords per tile row: [2 halo][256 px][2 halo][4 pad]
#define PTILE 1864    // 7 rows * 264 + 16 pad; %32==8 -> cg stride (2*PTILE) == 16 banks
#define NTHR  256

typedef __attribute__((ext_vector_type(2))) _Float16 half2_t;

static __device__ __forceinline__ half2_t u2h(unsigned u) { return __builtin_bit_cast(half2_t, u); }

static __device__ __forceinline__ unsigned pkrtz(float a, float b) {
    auto h = __builtin_amdgcn_cvt_pkrtz(a, b);   // __fp16 ext_vector(2), 4 bytes
    return __builtin_bit_cast(unsigned, h);
}

static __device__ __forceinline__ float dot2(half2_t a, half2_t b, float c) {
#if __has_builtin(__builtin_amdgcn_fdot2)
    return __builtin_amdgcn_fdot2(a, b, c, false);
#else
    return (float)a.x * (float)b.x + ((float)a.y * (float)b.y + c);
#endif
}

// Block = 2 output rows x 256 cols, 4 waves, 4 px/thread, channel-pair f16 tile.
// 8 stages x 8 channels (score: 32..63, output: 0..31), double-buffered LDS.
// Tile dword = half2(ch c, ch c+1) per pixel -> 2 ds_read_b128 per window row,
// v_dot2 = 2 MACs/instr for scores. Zeroed halo/OOB rows => implicit padding.
//
// PIPELINE NOTE (round 3): at __launch_bounds__(256,2) the real VGPR budget
// is 256 (LDS limits to 2 blocks/CU = 2 waves/SIMD), but the scheduler was
// compressing to 128 regs (the phantom 4-wave/SIMD step) by SINKING the 6
// prefetch loads down to their cvtwrite use -- turning the software pipeline
// into a synchronous load+wait+barrier convoy (~5.4us/stage, VALUBusy 29%).
// sched_barrier(0) after the prefetch pins the loads at the top of the stage
// so they overlap the stage's compute; RA must keep pa/pb live (~180 regs,
// still 2 waves/SIMD).
__global__ __launch_bounds__(NTHR, 2)
void local_attn_kernel(const float* __restrict__ x,
                       const float* __restrict__ kern,
                       float* __restrict__ out)
{
    __shared__ unsigned ldsu[2 * 4 * PTILE];
    __shared__ float kw[K2];

    const int tid = threadIdx.x;
    for (int i = tid; i < 2 * 4 * PTILE; i += NTHR) ldsu[i] = 0u;
    if (tid < K2) kw[tid] = kern[tid] * (1.0f / KS);

    const int lane = tid & 63;
    const int wv   = tid >> 6;
    const int ty   = wv >> 1;                       // output row in block
    const int cg   = lane >> 5;                     // pair-half (0/1)
    const int tx   = ((wv & 1) << 5) | (lane & 31); // pixel-group 0..63
    const int w0   = tx << 2;

    // XCD swizzle: each XCD owns a contiguous 32-row band (halo L2-shared)
    const int bx     = blockIdx.x;
    const int hgroup = ((bx & 7) << 4) | (bx >> 3);
    const int h0     = hgroup * 2;
    const int h      = h0 + ty;
    const int b      = blockIdx.y;

    const float* xb = x + (size_t)b * 64 * PLANE;

    // 6 staging tasks/thread: task i -> (pair, tile row, 4-px segment)
    int gofs[6], lofs[6], pofs[6];
#pragma unroll
    for (int i = 0; i < 6; ++i) {
        const int rp   = (tid >> 6) + 4 * i;        // 0..23 (wave-uniform)
        const int row  = rp % 6;
        const int pair = rp / 6;
        const int r    = h0 - 2 + row;
        const bool v   = (unsigned)r < (unsigned)HH;
        gofs[i] = min(max(r, 0), HH - 1) * WW + (tid & 63) * 4;
        pofs[i] = pair * 2 * PLANE;
        lofs[i] = pair * PTILE + (v ? row : 6) * LROWD + 2 + (tid & 63) * 4;
    }

    float4 pa[6], pb[6];
    auto prefetch = [&](int st) {
        const float* xc = xb + (size_t)((st < 4) ? 32 + st * 8 : (st - 4) * 8) * PLANE;
#pragma unroll
        for (int i = 0; i < 6; ++i) {
            pa[i] = *(const float4*)(xc + pofs[i] + gofs[i]);
            pb[i] = *(const float4*)(xc + pofs[i] + PLANE + gofs[i]);
        }
    };
    auto cvtwrite = [&](int bufi) {
        unsigned* lb = ldsu + bufi * 4 * PTILE;
#pragma unroll
        for (int i = 0; i < 6; ++i) {
            const unsigned d0 = pkrtz(pa[i].x, pb[i].x);
            const unsigned d1 = pkrtz(pa[i].y, pb[i].y);
            const unsigned d2 = pkrtz(pa[i].z, pb[i].z);
            const unsigned d3 = pkrtz(pa[i].w, pb[i].w);
            *(uint2*)(lb + lofs[i])     = make_uint2(d0, d1);
            *(uint2*)(lb + lofs[i] + 2) = make_uint2(d2, d3);
        }
    };

    float s[4][K2];
#pragma unroll
    for (int p = 0; p < 4; ++p)
#pragma unroll
        for (int k = 0; k < K2; ++k) s[p][k] = 0.0f;

    __syncthreads();          // zero-init + kw visible
    prefetch(0);
    cvtwrite(0);
    __syncthreads();

#pragma unroll 1
    for (int t = 0; t < 8; ++t) {
        if (t + 1 < 8) {
            prefetch(t + 1);
            // Pin the prefetch loads at the top of the stage: forbid the
            // scheduler from sinking them into the cvtwrite at the bottom
            // (which it does to save VGPRs, destroying the pipeline).
            __builtin_amdgcn_sched_barrier(0);
        }
        const unsigned* buf = ldsu + (t & 1) * 4 * PTILE;

        if (t < 4) {
            // ---- score: 2 channel-pairs per lane-half, dot2 accumulate ----
#pragma unroll
            for (int dp = 0; dp < 2; ++dp) {
                const unsigned* tb = buf + (cg * 2 + dp) * PTILE;
                half2_t ctr[4];
                {   // center row (i=2) first: f[q] = pair at px w0-2+q
                    const unsigned* rp = tb + (ty + 2) * LROWD + w0;
                    const uint4 r0 = *(const uint4*)(rp);
                    const uint4 r1 = *(const uint4*)(rp + 4);
                    half2_t f[8] = {u2h(r0.x), u2h(r0.y), u2h(r0.z), u2h(r0.w),
                                    u2h(r1.x), u2h(r1.y), u2h(r1.z), u2h(r1.w)};
#pragma unroll
                    for (int p = 0; p < 4; ++p) ctr[p] = f[p + 2];
#pragma unroll
                    for (int j = 0; j < KS; ++j)
#pragma unroll
                        for (int p = 0; p < 4; ++p)
                            s[p][2 * KS + j] = dot2(f[p + j], ctr[p], s[p][2 * KS + j]);
                }
#pragma unroll
                for (int i = 0; i < KS; ++i) {
                    if (i == 2) continue;
                    const unsigned* rp = tb + (ty + i) * LROWD + w0;
                    const uint4 r0 = *(const uint4*)(rp);
                    const uint4 r1 = *(const uint4*)(rp + 4);
                    half2_t f[8] = {u2h(r0.x), u2h(r0.y), u2h(r0.z), u2h(r0.w),
                                    u2h(r1.x), u2h(r1.y), u2h(r1.z), u2h(r1.w)};
#pragma unroll
                    for (int j = 0; j < KS; ++j)
#pragma unroll
                        for (int p = 0; p < 4; ++p)
                            s[p][i * KS + j] = dot2(f[p + j], ctr[p], s[p][i * KS + j]);
                }
            }
            if (t == 3) {
                // combine pair-halves, then softmax over 25 taps.
                // zero-padded taps score exactly 0 and keep their denominator
                // share (matches reference).
#pragma unroll
                for (int p = 0; p < 4; ++p)
#pragma unroll
                    for (int k = 0; k < K2; ++k)
                        s[p][k] += __shfl_xor(s[p][k], 32, 64);
#pragma unroll
                for (int p = 0; p < 4; ++p) {
                    float mx = -INFINITY;
#pragma unroll
                    for (int k = 0; k < K2; ++k) {
                        float v = s[p][k] * kw[k];
                        s[p][k] = v;
                        mx = fmaxf(mx, v);
                    }
                    float sum = 0.0f;
#pragma unroll
                    for (int k = 0; k < K2; ++k) {
                        float e = __expf(s[p][k] - mx);
                        s[p][k] = e;
                        sum += e;
                    }
                    const float inv = 1.0f / sum;
#pragma unroll
                    for (int k = 0; k < K2; ++k) s[p][k] *= inv;
                }
            }
        } else {
            // ---- output: weighted sum; fp32 accumulate via mixed FMA ----
            const int chb = (t - 4) * 8;
#pragma unroll
            for (int dp = 0; dp < 2; ++dp) {
                const unsigned* tb = buf + (cg * 2 + dp) * PTILE;
                float alo[4] = {0.f, 0.f, 0.f, 0.f};
                float ahi[4] = {0.f, 0.f, 0.f, 0.f};
#pragma unroll
                for (int i = 0; i < KS; ++i) {
                    const unsigned* rp = tb + (ty + i) * LROWD + w0;
                    const uint4 r0 = *(const uint4*)(rp);
                    const uint4 r1 = *(const uint4*)(rp + 4);
                    half2_t f[8] = {u2h(r0.x), u2h(r0.y), u2h(r0.z), u2h(r0.w),
                                    u2h(r1.x), u2h(r1.y), u2h(r1.z), u2h(r1.w)};
#pragma unroll
                    for (int j = 0; j < KS; ++j)
#pragma unroll
                        for (int p = 0; p < 4; ++p) {
                            const half2_t v = f[p + j];
                            const float  wgt = s[p][i * KS + j];
                            alo[p] = fmaf((float)v.x, wgt, alo[p]);
                            ahi[p] = fmaf((float)v.y, wgt, ahi[p]);
                        }
                }
                const int c0 = chb + (cg * 2 + dp) * 2;
                float* op = out + ((size_t)b * 32 + c0) * PLANE + h * WW + w0;
                *(float4*)op           = make_float4(alo[0], alo[1], alo[2], alo[3]);
                *(float4*)(op + PLANE) = make_float4(ahi[0], ahi[1], ahi[2], ahi[3]);
            }
        }

        if (t + 1 < 8) {
            cvtwrite((t + 1) & 1);
            __syncthreads();
        }
    }
}

extern "C" void kernel_launch(void* const* d_in, const int* in_sizes, int n_in,
                              void* d_out, int out_size, void* d_ws, size_t ws_size,
                              hipStream_t stream) {
    const float* x    = (const float*)d_in[0];
    const float* kern = (const float*)d_in[1];
    float*       out  = (float*)d_out;

    dim3 grid(HH / 2, BB, 1);
    dim3 block(NTHR, 1, 1);
    hipLaunchKernelGGL(local_attn_kernel, grid, block, 0, stream, x, kern, out);
}

// Round 4
// 107.580 us; speedup vs baseline: 1.2743x; 1.0682x over previous
//
#include <hip/hip_runtime.h>
#include <math.h>

#define KS    5
#define K2    25
#define BB    4
#define HH    256
#define WW    256
#define PLANE (HH * WW)
#define LROWD 264     // dwords per tile row: [2 halo][256 px][2 halo][4 pad]
#define PTILE 1864    // 7 rows * 264 + 16 pad; %32==8 -> cg stride (2*PTILE) == 16 banks
#define NTHR  256

typedef __attribute__((ext_vector_type(2))) _Float16 half2_t;
typedef __attribute__((ext_vector_type(4))) float    f32x4;

static __device__ __forceinline__ half2_t u2h(unsigned u) { return __builtin_bit_cast(half2_t, u); }

static __device__ __forceinline__ unsigned pkrtz(float a, float b) {
    auto h = __builtin_amdgcn_cvt_pkrtz(a, b);   // __fp16 ext_vector(2), 4 bytes
    return __builtin_bit_cast(unsigned, h);
}

static __device__ __forceinline__ float dot2(half2_t a, half2_t b, float c) {
#if __has_builtin(__builtin_amdgcn_fdot2)
    return __builtin_amdgcn_fdot2(a, b, c, false);
#else
    return (float)a.x * (float)b.x + ((float)a.y * (float)b.y + c);
#endif
}

// Block = 2 output rows x 256 cols, 4 waves, 4 px/thread, channel-pair f16 tile.
// 8 stages x 8 channels (score: 32..63, output: 0..31), double-buffered LDS.
// Tile dword = half2(ch c, ch c+1) per pixel -> 2 ds_read_b128 per window row,
// v_dot2 = 2 MACs/instr for scores. Zeroed halo/OOB rows => implicit padding.
//
// PIPELINE NOTE (round 4): the compiler was sinking the 6x2 prefetch loads
// from the stage top into cvtwrite at the stage bottom (MachineSink, cross-
// block -- sched_barrier(0) can't stop it; VGPR stuck at the 128 occupancy
// step both rounds). That exposes full load latency inside the vmcnt-drain+
// barrier convoy each stage. Fix: issue the loads as volatile inline asm
// (side-effecting => unsinkable, program-order pinned at stage top), and do
// the vmcnt wait manually at the top of cvtwrite (compiler can't track asm
// loads), followed by sched_barrier(0) so the pkrtz/ds_writes aren't hoisted
// above the wait (rule: scheduler hoists past asm waitcnt despite data deps).
// pa/pb now stay live across the stage compute: ~180 VGPR, still within the
// 256-reg budget at 2 waves/SIMD (LDS-bound occupancy unchanged).
__global__ __launch_bounds__(NTHR, 2)
void local_attn_kernel(const float* __restrict__ x,
                       const float* __restrict__ kern,
                       float* __restrict__ out)
{
    __shared__ unsigned ldsu[2 * 4 * PTILE];
    __shared__ float kw[K2];

    const int tid = threadIdx.x;
    for (int i = tid; i < 2 * 4 * PTILE; i += NTHR) ldsu[i] = 0u;
    if (tid < K2) kw[tid] = kern[tid] * (1.0f / KS);

    const int lane = tid & 63;
    const int wv   = tid >> 6;
    const int ty   = wv >> 1;                       // output row in block
    const int cg   = lane >> 5;                     // pair-half (0/1)
    const int tx   = ((wv & 1) << 5) | (lane & 31); // pixel-group 0..63
    const int w0   = tx << 2;

    // XCD swizzle: each XCD owns a contiguous 32-row band (halo L2-shared)
    const int bx     = blockIdx.x;
    const int hgroup = ((bx & 7) << 4) | (bx >> 3);
    const int h0     = hgroup * 2;
    const int h      = h0 + ty;
    const int b      = blockIdx.y;

    const float* xb = x + (size_t)b * 64 * PLANE;

    // 6 staging tasks/thread: task i -> (pair, tile row, 4-px segment)
    int gofs[6], lofs[6], pofs[6];
#pragma unroll
    for (int i = 0; i < 6; ++i) {
        const int rp   = (tid >> 6) + 4 * i;        // 0..23 (wave-uniform)
        const int row  = rp % 6;
        const int pair = rp / 6;
        const int r    = h0 - 2 + row;
        const bool v   = (unsigned)r < (unsigned)HH;
        gofs[i] = min(max(r, 0), HH - 1) * WW + (tid & 63) * 4;
        pofs[i] = pair * 2 * PLANE;
        lofs[i] = pair * PTILE + (v ? row : 6) * LROWD + 2 + (tid & 63) * 4;
    }

    f32x4 pa[6], pb[6];
    auto prefetch = [&](int st) {
        const float* xc = xb + (size_t)((st < 4) ? 32 + st * 8 : (st - 4) * 8) * PLANE;
#pragma unroll
        for (int i = 0; i < 6; ++i) {
            const float* p0 = xc + pofs[i] + gofs[i];
            const float* p1 = p0 + PLANE;
            // volatile asm: unsinkable, pinned at stage top in program order
            asm volatile("global_load_dwordx4 %0, %1, off"
                         : "=v"(pa[i]) : "v"(p0));
            asm volatile("global_load_dwordx4 %0, %1, off"
                         : "=v"(pb[i]) : "v"(p1));
        }
        // keep compute below the load pack (scheduler-level)
        __builtin_amdgcn_sched_barrier(0);
    };
    auto cvtwrite = [&](int bufi) {
        // compiler can't track the asm loads' vmcnt -- wait manually, and
        // fence the scheduler so pkrtz/ds_write can't hoist above the wait.
        asm volatile("s_waitcnt vmcnt(0)" ::: "memory");
        __builtin_amdgcn_sched_barrier(0);
        unsigned* lb = ldsu + bufi * 4 * PTILE;
#pragma unroll
        for (int i = 0; i < 6; ++i) {
            const unsigned d0 = pkrtz(pa[i].x, pb[i].x);
            const unsigned d1 = pkrtz(pa[i].y, pb[i].y);
            const unsigned d2 = pkrtz(pa[i].z, pb[i].z);
            const unsigned d3 = pkrtz(pa[i].w, pb[i].w);
            *(uint2*)(lb + lofs[i])     = make_uint2(d0, d1);
            *(uint2*)(lb + lofs[i] + 2) = make_uint2(d2, d3);
        }
    };

    float s[4][K2];
#pragma unroll
    for (int p = 0; p < 4; ++p)
#pragma unroll
        for (int k = 0; k < K2; ++k) s[p][k] = 0.0f;

    __syncthreads();          // zero-init + kw visible
    prefetch(0);
    cvtwrite(0);
    __syncthreads();

#pragma unroll 1
    for (int t = 0; t < 8; ++t) {
        if (t + 1 < 8) prefetch(t + 1);
        const unsigned* buf = ldsu + (t & 1) * 4 * PTILE;

        if (t < 4) {
            // ---- score: 2 channel-pairs per lane-half, dot2 accumulate ----
#pragma unroll
            for (int dp = 0; dp < 2; ++dp) {
                const unsigned* tb = buf + (cg * 2 + dp) * PTILE;
                half2_t ctr[4];
                {   // center row (i=2) first: f[q] = pair at px w0-2+q
                    const unsigned* rp = tb + (ty + 2) * LROWD + w0;
                    const uint4 r0 = *(const uint4*)(rp);
                    const uint4 r1 = *(const uint4*)(rp + 4);
                    half2_t f[8] = {u2h(r0.x), u2h(r0.y), u2h(r0.z), u2h(r0.w),
                                    u2h(r1.x), u2h(r1.y), u2h(r1.z), u2h(r1.w)};
#pragma unroll
                    for (int p = 0; p < 4; ++p) ctr[p] = f[p + 2];
#pragma unroll
                    for (int j = 0; j < KS; ++j)
#pragma unroll
                        for (int p = 0; p < 4; ++p)
                            s[p][2 * KS + j] = dot2(f[p + j], ctr[p], s[p][2 * KS + j]);
                }
#pragma unroll
                for (int i = 0; i < KS; ++i) {
                    if (i == 2) continue;
                    const unsigned* rp = tb + (ty + i) * LROWD + w0;
                    const uint4 r0 = *(const uint4*)(rp);
                    const uint4 r1 = *(const uint4*)(rp + 4);
                    half2_t f[8] = {u2h(r0.x), u2h(r0.y), u2h(r0.z), u2h(r0.w),
                                    u2h(r1.x), u2h(r1.y), u2h(r1.z), u2h(r1.w)};
#pragma unroll
                    for (int j = 0; j < KS; ++j)
#pragma unroll
                        for (int p = 0; p < 4; ++p)
                            s[p][i * KS + j] = dot2(f[p + j], ctr[p], s[p][i * KS + j]);
                }
            }
            if (t == 3) {
                // combine pair-halves, then softmax over 25 taps.
                // zero-padded taps score exactly 0 and keep their denominator
                // share (matches reference).
#pragma unroll
                for (int p = 0; p < 4; ++p)
#pragma unroll
                    for (int k = 0; k < K2; ++k)
                        s[p][k] += __shfl_xor(s[p][k], 32, 64);
#pragma unroll
                for (int p = 0; p < 4; ++p) {
                    float mx = -INFINITY;
#pragma unroll
                    for (int k = 0; k < K2; ++k) {
                        float v = s[p][k] * kw[k];
                        s[p][k] = v;
                        mx = fmaxf(mx, v);
                    }
                    float sum = 0.0f;
#pragma unroll
                    for (int k = 0; k < K2; ++k) {
                        float e = __expf(s[p][k] - mx);
                        s[p][k] = e;
                        sum += e;
                    }
                    const float inv = 1.0f / sum;
#pragma unroll
                    for (int k = 0; k < K2; ++k) s[p][k] *= inv;
                }
            }
        } else {
            // ---- output: weighted sum; fp32 accumulate via mixed FMA ----
            const int chb = (t - 4) * 8;
#pragma unroll
            for (int dp = 0; dp < 2; ++dp) {
                const unsigned* tb = buf + (cg * 2 + dp) * PTILE;
                float alo[4] = {0.f, 0.f, 0.f, 0.f};
                float ahi[4] = {0.f, 0.f, 0.f, 0.f};
#pragma unroll
                for (int i = 0; i < KS; ++i) {
                    const unsigned* rp = tb + (ty + i) * LROWD + w0;
                    const uint4 r0 = *(const uint4*)(rp);
                    const uint4 r1 = *(const uint4*)(rp + 4);
                    half2_t f[8] = {u2h(r0.x), u2h(r0.y), u2h(r0.z), u2h(r0.w),
                                    u2h(r1.x), u2h(r1.y), u2h(r1.z), u2h(r1.w)};
#pragma unroll
                    for (int j = 0; j < KS; ++j)
#pragma unroll
                        for (int p = 0; p < 4; ++p) {
                            const half2_t v = f[p + j];
                            const float  wgt = s[p][i * KS + j];
                            alo[p] = fmaf((float)v.x, wgt, alo[p]);
                            ahi[p] = fmaf((float)v.y, wgt, ahi[p]);
                        }
                }
                const int c0 = chb + (cg * 2 + dp) * 2;
                float* op = out + ((size_t)b * 32 + c0) * PLANE + h * WW + w0;
                *(float4*)op           = make_float4(alo[0], alo[1], alo[2], alo[3]);
                *(float4*)(op + PLANE) = make_float4(ahi[0], ahi[1], ahi[2], ahi[3]);
            }
        }

        if (t + 1 < 8) {
            cvtwrite((t + 1) & 1);
            __syncthreads();
        }
    }
}

extern "C" void kernel_launch(void* const* d_in, const int* in_sizes, int n_in,
                              void* d_out, int out_size, void* d_ws, size_t ws_size,
                              hipStream_t stream) {
    const float* x    = (const float*)d_in[0];
    const float* kern = (const float*)d_in[1];
    float*       out  = (float*)d_out;

    dim3 grid(HH / 2, BB, 1);
    dim3 block(NTHR, 1, 1);
    hipLaunchKernelGGL(local_attn_kernel, grid, block, 0, stream, x, kern, out);
}